// Round 1
// baseline (1042.541 us; speedup 1.0000x reference)
//
#include <hip/hip_runtime.h>

// BetterPixelBilateralFilter2: joint bilateral, B=2 C=32 H=720 W=1280, K=5 dil=3, out ch 0..2
constexpr int H = 720, W = 1280;
constexpr int HWp = H * W;
constexpr int NCH = 66;          // input channels: 32 filterable + 32 scale + psy + psx
constexpr int C = 32;
constexpr int KOUT = 3;
constexpr int TX = 64, TY = 16;  // output tile per block (256 threads, 4 px/thread in x)
constexpr int LW = 80, LH = 28;  // halo'd tile: cols [gx0-8, gx0+71], rows [gy0-6, gy0+21]
constexpr int F4PR = LW / 4;     // 20 float4 per LDS row
constexpr int NF4 = LH * F4PR;   // 560 float4 per buffer
constexpr int NBUF = 5;          // bufs 0..2 persistent (ch 0..2), 3..4 rotate

static_assert(W % TX == 0 && H % TY == 0, "exact tiling");

__device__ __forceinline__ float softplusf(float x) {
  // jax.nn.softplus = max(x,0) + log1p(exp(-|x|))
  return fmaxf(x, 0.f) + log1pf(__expf(-fabsf(x)));
}

__global__ __launch_bounds__(256) void bilat_kernel(
    const float* __restrict__ in,
    const float* __restrict__ coeffs,
    float* __restrict__ out) {
  __shared__ float4 lds4[NBUF][NF4];   // 44.8 KB

  const int tx = threadIdx.x;          // 0..15
  const int ty = threadIdx.y;          // 0..15
  const int tid = ty * 16 + tx;
  const int b = blockIdx.z;
  const int gx0 = blockIdx.x * TX;
  const int gy0 = blockIdx.y * TY;
  const int lx = 4 * tx;               // local col of first of this thread's 4 pixels
  const int gy = gy0 + ty;             // this thread's pixel row
  const int gxp = gx0 + lx;            // global col of first pixel

  const float* __restrict__ batch = in + (size_t)b * NCH * HWp;

  // Staging offsets: 560 float4s per channel tile, 256 threads -> 3 rounds.
  // Clamped to valid memory; out-of-image values are garbage-but-finite and are
  // later killed by the validity mask (w=0). Clamps preserve 16B alignment.
  int s_off[3];
  #pragma unroll
  for (int it = 0; it < 3; ++it) {
    int idx = tid + it * 256;
    int idq = idx < NF4 ? idx : NF4 - 1;
    int r = idq / F4PR;
    int c4 = idq - r * F4PR;
    int gyy = gy0 + r - 6;
    int cy = gyy < 0 ? 0 : (gyy > H - 1 ? H - 1 : gyy);
    int off = cy * W + gx0 + c4 * 4 - 8;
    off = off < 0 ? 0 : (off > HWp - 4 ? HWp - 4 : off);
    s_off[it] = off;
  }

  float logw[4][25];
  #pragma unroll
  for (int p = 0; p < 4; ++p)
    #pragma unroll
    for (int t = 0; t < 25; ++t) logw[p][t] = 0.f;

  // stage channel 0 into buffer 0
  {
    const float* plane = batch;
    float4 st0 = *(const float4*)(plane + s_off[0]);
    float4 st1 = *(const float4*)(plane + s_off[1]);
    float4 st2 = *(const float4*)(plane + s_off[2]);
    lds4[0][tid] = st0;
    lds4[0][tid + 256] = st1;
    if (tid + 512 < NF4) lds4[0][tid + 512] = st2;
  }
  __syncthreads();

  // ---- Phase A: accumulate logw over all 32 channels ----
  #pragma unroll 1
  for (int c = 0; c < C; ++c) {
    const int bf = c < 3 ? c : 3 + (c & 1);
    // prefetch next channel's tile into registers (latency hidden under compute)
    float4 st0, st1, st2;
    const bool pre = (c + 1 < C);
    if (pre) {
      const float* plane = batch + (size_t)(c + 1) * HWp;
      st0 = *(const float4*)(plane + s_off[0]);
      st1 = *(const float4*)(plane + s_off[1]);
      st2 = *(const float4*)(plane + s_off[2]);
    }
    // per-pixel channel coefficient: pc = -exp(coeffs[c]) * softplus(scale[c])
    float4 sc = *(const float4*)(batch + (size_t)(C + c) * HWp + (size_t)gy * W + gxp);
    float ec = __expf(coeffs[c]);
    float pc[4] = {-ec * softplusf(sc.x), -ec * softplusf(sc.y),
                   -ec * softplusf(sc.z), -ec * softplusf(sc.w)};

    const float* buf = (const float*)lds4[bf];
    float fr[4];
    // tap rows: LDS row = ty + 3*rr; process rr=2 (center) first to grab fr
    constexpr int RRO[5] = {2, 0, 1, 3, 4};
    #pragma unroll
    for (int i = 0; i < 5; ++i) {
      const int rr = RRO[i];
      const float* rowp = buf + (ty + 3 * rr) * LW + lx;
      float v[20];
      #pragma unroll
      for (int q = 0; q < 5; ++q) {
        float4 t4 = *(const float4*)(rowp + 4 * q);
        v[4 * q + 0] = t4.x; v[4 * q + 1] = t4.y;
        v[4 * q + 2] = t4.z; v[4 * q + 3] = t4.w;
      }
      if (i == 0) {  // center row: f values are v[8..11]
        fr[0] = v[8]; fr[1] = v[9]; fr[2] = v[10]; fr[3] = v[11];
      }
      #pragma unroll
      for (int p = 0; p < 4; ++p) {
        #pragma unroll
        for (int cc = 0; cc < 5; ++cc) {
          float d = fr[p] - v[p + 3 * cc + 2];
          logw[p][rr * 5 + cc] = fmaf(pc[p] * d, d, logw[p][rr * 5 + cc]);
        }
      }
    }
    if (pre) {
      const int nbf = (c + 1) < 3 ? (c + 1) : 3 + ((c + 1) & 1);
      lds4[nbf][tid] = st0;
      lds4[nbf][tid + 256] = st1;
      if (tid + 512 < NF4) lds4[nbf][tid + 512] = st2;
    }
    __syncthreads();
  }

  // ---- Phase B: weights, den, num over channels 0..2, output ----
  float4 sy4 = *(const float4*)(batch + (size_t)(2 * C + 0) * HWp + (size_t)gy * W + gxp);
  float4 sx4 = *(const float4*)(batch + (size_t)(2 * C + 1) * HWp + (size_t)gy * W + gxp);
  float eY = __expf(coeffs[C + 0]);
  float eX = __expf(coeffs[C + 1]);
  float psy[4] = {-eY * softplusf(sy4.x), -eY * softplusf(sy4.y),
                  -eY * softplusf(sy4.z), -eY * softplusf(sy4.w)};
  float psx[4] = {-eX * softplusf(sx4.x), -eX * softplusf(sx4.y),
                  -eX * softplusf(sx4.z), -eX * softplusf(sx4.w)};

  // convert logw -> w in place (logw <= 0 always, so exp never overflows)
  #pragma unroll
  for (int rr = 0; rr < 5; ++rr) {
    const int dyo = 3 * (rr - 2);
    const float dy2 = (float)((rr - 2) * (rr - 2));
    const bool vy = (unsigned)(gy + dyo) < (unsigned)H;
    #pragma unroll
    for (int cc = 0; cc < 5; ++cc) {
      const int dxo = 3 * (cc - 2);
      const float dx2 = (float)((cc - 2) * (cc - 2));
      #pragma unroll
      for (int p = 0; p < 4; ++p) {
        const bool vx = (unsigned)(gxp + p + dxo) < (unsigned)W;
        float lw = logw[p][rr * 5 + cc] + psy[p] * dy2 + psx[p] * dx2;
        logw[p][rr * 5 + cc] = (vy && vx) ? __expf(lw) : 0.f;
      }
    }
  }

  float den[4] = {0.f, 0.f, 0.f, 0.f};
  #pragma unroll
  for (int t = 0; t < 25; ++t)
    #pragma unroll
    for (int p = 0; p < 4; ++p) den[p] += logw[p][t];

  float num[KOUT][4];
  #pragma unroll
  for (int k = 0; k < KOUT; ++k)
    #pragma unroll
    for (int p = 0; p < 4; ++p) num[k][p] = 0.f;

  #pragma unroll
  for (int rr = 0; rr < 5; ++rr) {
    #pragma unroll
    for (int k = 0; k < KOUT; ++k) {
      const float* rowp = (const float*)lds4[k] + (ty + 3 * rr) * LW + lx;
      float v[20];
      #pragma unroll
      for (int q = 0; q < 5; ++q) {
        float4 t4 = *(const float4*)(rowp + 4 * q);
        v[4 * q + 0] = t4.x; v[4 * q + 1] = t4.y;
        v[4 * q + 2] = t4.z; v[4 * q + 3] = t4.w;
      }
      #pragma unroll
      for (int cc = 0; cc < 5; ++cc)
        #pragma unroll
        for (int p = 0; p < 4; ++p)
          num[k][p] = fmaf(logw[p][rr * 5 + cc], v[p + 3 * cc + 2], num[k][p]);
    }
  }

  #pragma unroll
  for (int k = 0; k < KOUT; ++k) {
    float4 o;
    o.x = num[k][0] / den[0];
    o.y = num[k][1] / den[1];
    o.z = num[k][2] / den[2];
    o.w = num[k][3] / den[3];
    *(float4*)(out + ((size_t)b * KOUT + k) * HWp + (size_t)gy * W + gxp) = o;
  }
}

extern "C" void kernel_launch(void* const* d_in, const int* in_sizes, int n_in,
                              void* d_out, int out_size, void* d_ws, size_t ws_size,
                              hipStream_t stream) {
  const float* in = (const float*)d_in[0];      // (2, 66, 720, 1280) f32
  const float* coeffs = (const float*)d_in[1];  // (1, 34, 1, 1) f32
  float* out = (float*)d_out;                   // (2, 3, 720, 1280) f32
  dim3 grid(W / TX, H / TY, 2);
  dim3 block(16, 16);
  hipLaunchKernelGGL(bilat_kernel, grid, block, 0, stream, in, coeffs, out);
}